// Round 1
// baseline (2010.590 us; speedup 1.0000x reference)
//
#include <hip/hip_runtime.h>
#include <cstdint>

// LatentCube: 4x { sin_sobel -> instance_norm -> dynamic MLP residual }, then channel mean.
// B=16, NF=64, FIN=448, CUBE=16^3=4096 voxels, LAT=4096, TOTAL=65728.

#define B_     16
#define NF_    64
#define FIN_   448
#define LAT_   4096
#define TOTAL_ 65728
#define VOX_   4096

typedef unsigned short u16;
typedef __attribute__((ext_vector_type(8))) short short8;
typedef __attribute__((ext_vector_type(4))) float floatx4;
typedef __attribute__((ext_vector_type(4))) unsigned short ushortx4;

__device__ __forceinline__ u16 f2bf(float f) {
    uint32_t u = __float_as_uint(f);
    u += 0x7FFFu + ((u >> 16) & 1u);   // round-to-nearest-even
    return (u16)(u >> 16);
}

// ---------------- init: out[b] = seed ----------------
__global__ __launch_bounds__(256) void k_init(const float* __restrict__ seed,
                                              float* __restrict__ out) {
    int i = blockIdx.x * 256 + threadIdx.x;           // exactly 16*64*4096 threads
    out[i] = seed[i & (NF_ * VOX_ - 1)];
}

// ---------------- hyper GEMM: part[split][r][j] = sum_k lat[r][k] * wh[k][j] ----------------
__global__ __launch_bounds__(256) void k_hyper(const float* __restrict__ lat,
                                               const float* __restrict__ wh,
                                               float* __restrict__ part) {
    __shared__ float latl[128 * 16];                  // [kl][r]
    int j = blockIdx.x * 256 + threadIdx.x;
    int koff = blockIdx.y * 1024;                     // 4-way K split
    float acc[16];
#pragma unroll
    for (int r = 0; r < 16; r++) acc[r] = 0.f;
    bool act = j < TOTAL_;
    for (int kc = 0; kc < 1024; kc += 128) {
        __syncthreads();
#pragma unroll
        for (int t = 0; t < 8; t++) {
            int i = threadIdx.x + t * 256;
            int r = i >> 7, kl = i & 127;
            latl[kl * 16 + r] = lat[r * LAT_ + koff + kc + kl];
        }
        __syncthreads();
        if (act) {
            const float* wp = wh + (size_t)(koff + kc) * TOTAL_ + j;
            for (int kl = 0; kl < 128; kl++) {
                float wv = wp[(size_t)kl * TOTAL_];
                const float* lp = latl + kl * 16;
#pragma unroll
                for (int r = 0; r < 16; r++) acc[r] = fmaf(lp[r], wv, acc[r]);
            }
        }
    }
    if (act) {
        float* o = part + (size_t)blockIdx.y * (16 * TOTAL_) + j;
#pragma unroll
        for (int r = 0; r < 16; r++) o[(size_t)r * TOTAL_] = acc[r];
    }
}

// ---------------- reduce K-splits + b_hyper -> ks ----------------
__global__ __launch_bounds__(256) void k_redks(const float* __restrict__ part,
                                               const float* __restrict__ bh,
                                               float* __restrict__ ks) {
    int idx = blockIdx.x * 256 + threadIdx.x;
    if (idx >= 16 * TOTAL_) return;
    int j = idx % TOTAL_;
    float s = bh[j];
#pragma unroll
    for (int sp = 0; sp < 4; sp++) s += part[(size_t)sp * (16 * TOTAL_) + idx];
    ks[idx] = s;
}

// ---------------- weight prep: f32 ks -> bf16 Wcomb(128x448: w_in|w_sk), Wmid, Wout ----------------
__global__ __launch_bounds__(256) void k_wprep(const float* __restrict__ ks,
                                               u16* __restrict__ Wc,
                                               u16* __restrict__ Wm,
                                               u16* __restrict__ Wo) {
    int id = blockIdx.x * 256 + threadIdx.x;          // exactly 16*65536 threads
    int b = id >> 16, r = id & 65535;
    const float* kb = ks + (size_t)b * TOTAL_;
    if (r < 57344) {                                  // 128*448
        int fc = r / 448, c = r - fc * 448;
        float v = (fc < 64) ? kb[fc * 448 + c] : kb[37056 + (fc - 64) * 448 + c];
        Wc[(size_t)b * 57344 + r] = f2bf(v);
    } else if (r < 61440) {                           // w_mid 64x64
        int i = r - 57344;
        Wm[b * 4096 + i] = f2bf(kb[28736 + i]);
    } else {                                          // w_out 64x64
        int i = r - 61440;
        Wo[b * 4096 + i] = f2bf(kb[32896 + i]);
    }
}

// ---------------- sobel + sin + instance_norm ----------------
__device__ __forceinline__ void norm_write(float* vals, u16* dst, float* red, int tid) {
    float s = 0.f, ss = 0.f;
#pragma unroll
    for (int u = 0; u < 16; u++) { s += vals[u]; ss += vals[u] * vals[u]; }
#pragma unroll
    for (int off = 32; off > 0; off >>= 1) {
        s += __shfl_down(s, off);
        ss += __shfl_down(ss, off);
    }
    __syncthreads();                                  // protect red[] from previous channel
    if ((tid & 63) == 0) { red[tid >> 6] = s; red[4 + (tid >> 6)] = ss; }
    __syncthreads();
    float S = red[0] + red[1] + red[2] + red[3];
    float SS = red[4] + red[5] + red[6] + red[7];
    float mean = S * (1.f / 4096.f);
    float var = SS * (1.f / 4096.f) - mean * mean;
    float inv = rsqrtf(var + 1e-5f);
    union { u16 s[8]; uint4 v; } pk;
    uint4* p = (uint4*)(dst + tid * 16);
#pragma unroll
    for (int half = 0; half < 2; half++) {
#pragma unroll
        for (int u = 0; u < 8; u++) pk.s[u] = f2bf((vals[half * 8 + u] - mean) * inv);
        p[half] = pk.v;
    }
}

__global__ __launch_bounds__(256) void k_sobel(const float* __restrict__ out,
                                               u16* __restrict__ h) {
    int c = blockIdx.x, b = blockIdx.y, tid = threadIdx.x;
    __shared__ __align__(16) float cube[20 * 20 * 20];
    __shared__ float w3[3][27];
    __shared__ float w5[3][125];
    __shared__ float red[8];
    for (int i = tid; i < 27; i += 256) {
        float ra = (float)(i / 9) - 1.f, rb = (float)((i / 3) % 3) - 1.f, rc = (float)(i % 3) - 1.f;
        float d = ra * ra + rb * rb + rc * rc; if (d == 0.f) d = 1.f;
        w3[0][i] = ra / d; w3[1][i] = rb / d; w3[2][i] = rc / d;
    }
    for (int i = tid; i < 125; i += 256) {
        float ra = (float)(i / 25) - 2.f, rb = (float)((i / 5) % 5) - 2.f, rc = (float)(i % 5) - 2.f;
        float d = ra * ra + rb * rb + rc * rc; if (d == 0.f) d = 1.f;
        w5[0][i] = ra / d; w5[1][i] = rb / d; w5[2][i] = rc / d;
    }
    const float* src = out + (size_t)(b * NF_ + c) * VOX_;
    for (int i = tid; i < 8000; i += 256) {
        int pz = i / 400, rem = i - pz * 400, py = rem / 20, px = rem - py * 20;
        float v = 0.f;
        int z = pz - 2, y = py - 2, x = px - 2;
        if (((unsigned)z < 16u) & ((unsigned)y < 16u) & ((unsigned)x < 16u))
            v = src[(z << 8) + (y << 4) + x];
        cube[i] = v;
    }
    __syncthreads();
    int z = tid >> 4, y = tid & 15;                   // thread owns one x-row (16 voxels)
    float v0[16], v1[16], v2[16];

    // identity channel: sin(x)
    {
        const float* rp = cube + (z + 2) * 400 + (y + 2) * 20 + 2;
#pragma unroll
        for (int u = 0; u < 16; u++) v0[u] = __sinf(rp[u]);
        norm_write(v0, h + (size_t)(b * FIN_ + c) * VOX_, red, tid);
    }
    // k=3 group (3 dirs at once)
    {
#pragma unroll
        for (int u = 0; u < 16; u++) { v0[u] = 0.f; v1[u] = 0.f; v2[u] = 0.f; }
        for (int a = 0; a < 3; a++)
            for (int bb = 0; bb < 3; bb++) {
                const float* rp = cube + (z + a + 1) * 400 + (y + bb + 1) * 20;
                float rr[20];
#pragma unroll
                for (int t = 0; t < 5; t++) {
                    floatx4 q4 = *(const floatx4*)(rp + 4 * t);
                    rr[4 * t] = q4[0]; rr[4 * t + 1] = q4[1]; rr[4 * t + 2] = q4[2]; rr[4 * t + 3] = q4[3];
                }
                int ib = (a * 3 + bb) * 3;
#pragma unroll
                for (int cc = 0; cc < 3; cc++) {
                    float w0 = w3[0][ib + cc], w1 = w3[1][ib + cc], w2 = w3[2][ib + cc];
#pragma unroll
                    for (int xo = 0; xo < 16; xo++) {
                        float cv = rr[xo + cc + 1];
                        v0[xo] = fmaf(cv, w0, v0[xo]);
                        v1[xo] = fmaf(cv, w1, v1[xo]);
                        v2[xo] = fmaf(cv, w2, v2[xo]);
                    }
                }
            }
#pragma unroll
        for (int u = 0; u < 16; u++) { v0[u] = __sinf(v0[u]); v1[u] = __sinf(v1[u]); v2[u] = __sinf(v2[u]); }
        norm_write(v0, h + (size_t)(b * FIN_ + 64 + 3 * c + 0) * VOX_, red, tid);
        norm_write(v1, h + (size_t)(b * FIN_ + 64 + 3 * c + 1) * VOX_, red, tid);
        norm_write(v2, h + (size_t)(b * FIN_ + 64 + 3 * c + 2) * VOX_, red, tid);
    }
    // k=5 group
    {
#pragma unroll
        for (int u = 0; u < 16; u++) { v0[u] = 0.f; v1[u] = 0.f; v2[u] = 0.f; }
        for (int a = 0; a < 5; a++)
            for (int bb = 0; bb < 5; bb++) {
                const float* rp = cube + (z + a) * 400 + (y + bb) * 20;
                float rr[20];
#pragma unroll
                for (int t = 0; t < 5; t++) {
                    floatx4 q4 = *(const floatx4*)(rp + 4 * t);
                    rr[4 * t] = q4[0]; rr[4 * t + 1] = q4[1]; rr[4 * t + 2] = q4[2]; rr[4 * t + 3] = q4[3];
                }
                int ib = (a * 5 + bb) * 5;
#pragma unroll
                for (int cc = 0; cc < 5; cc++) {
                    float w0 = w5[0][ib + cc], w1 = w5[1][ib + cc], w2 = w5[2][ib + cc];
#pragma unroll
                    for (int xo = 0; xo < 16; xo++) {
                        float cv = rr[xo + cc];
                        v0[xo] = fmaf(cv, w0, v0[xo]);
                        v1[xo] = fmaf(cv, w1, v1[xo]);
                        v2[xo] = fmaf(cv, w2, v2[xo]);
                    }
                }
            }
#pragma unroll
        for (int u = 0; u < 16; u++) { v0[u] = __sinf(v0[u]); v1[u] = __sinf(v1[u]); v2[u] = __sinf(v2[u]); }
        norm_write(v0, h + (size_t)(b * FIN_ + 256 + 3 * c + 0) * VOX_, red, tid);
        norm_write(v1, h + (size_t)(b * FIN_ + 256 + 3 * c + 1) * VOX_, red, tid);
        norm_write(v2, h + (size_t)(b * FIN_ + 256 + 3 * c + 2) * VOX_, red, tid);
    }
}

// ---------------- dynamic MLP + residual, MFMA bf16 ----------------
// wg = 4 waves, covers 64 spatial; wave w owns n-tile of 16 spatial columns.
// Stage1: [W_in;W_sk](128x448) @ X(448x64) ; Stage2/3: 64x64 GEMMs via per-wave LDS.
#define XSTR 456   // LDS row stride (bf16 elems): 912 B, 16B-aligned
#define HSTR 72    // h1/h2 row stride (bf16 elems): 144 B, 16B-aligned
__global__ __launch_bounds__(256) void k_gemm(const u16* __restrict__ h,
                                              const u16* __restrict__ Wc,
                                              const u16* __restrict__ Wm,
                                              const u16* __restrict__ Wo,
                                              const float* __restrict__ ks,
                                              float* __restrict__ out) {
    __shared__ __align__(16) u16 Xl[64 * XSTR];
    int tid = threadIdx.x;
    int b = blockIdx.y, s0 = blockIdx.x * 64;
    // stage X tile transposed: Xl[s][c]
    const u16* hb = h + (size_t)b * FIN_ * VOX_ + s0;
    for (int i = tid; i < FIN_ * 32; i += 256) {
        int c = i >> 5, sp = i & 31;
        uint32_t v = *(const uint32_t*)(hb + (size_t)c * VOX_ + 2 * sp);
        Xl[(2 * sp) * XSTR + c] = (u16)(v & 0xFFFFu);
        Xl[(2 * sp + 1) * XSTR + c] = (u16)(v >> 16);
    }
    __syncthreads();
    int w = tid >> 6, lane = tid & 63, q = lane >> 4, m = lane & 15;
    const u16* Bp = Xl + (w * 16 + m) * XSTR + q * 8;
    const u16* Ap = Wc + ((size_t)b * 128 + m) * 448 + q * 8;
    floatx4 acc[8];
#pragma unroll
    for (int i = 0; i < 8; i++) acc[i] = (floatx4)(0.f);
    for (int k0 = 0; k0 < 448; k0 += 32) {
        short8 bf = *(const short8*)(Bp + k0);
#pragma unroll
        for (int mt = 0; mt < 8; mt++) {
            short8 af = *(const short8*)(Ap + (size_t)mt * (16 * 448) + k0);
            acc[mt] = __builtin_amdgcn_mfma_f32_16x16x32_bf16(af, bf, acc[mt], 0, 0, 0);
        }
    }
    const float* ksb = ks + (size_t)b * TOTAL_;
    u16* h1p = Xl + (w * 16) * XSTR;      // wave-private region (its own X rows, now dead)
    u16* h2p = h1p + 16 * HSTR;
    // h1 = relu(S[0:64] + b_in), store [s][c] bf16
#pragma unroll
    for (int mt = 0; mt < 4; mt++) {
        ushortx4 pk;
#pragma unroll
        for (int r = 0; r < 4; r++) {
            int f = mt * 16 + q * 4 + r;
            float v = acc[mt][r] + ksb[28672 + f];
            pk[r] = f2bf(fmaxf(v, 0.f));
        }
        *(ushortx4*)(h1p + m * HSTR + mt * 16 + q * 4) = pk;
    }
    // h2 = relu(Wmid @ h1 + b_mid)
    floatx4 acc2[4];
#pragma unroll
    for (int i = 0; i < 4; i++) acc2[i] = (floatx4)(0.f);
    const u16* Am = Wm + ((size_t)b * 64 + m) * 64 + q * 8;
#pragma unroll
    for (int k0 = 0; k0 < 64; k0 += 32) {
        short8 bf = *(const short8*)(h1p + m * HSTR + k0 + q * 8);
#pragma unroll
        for (int mt = 0; mt < 4; mt++) {
            short8 af = *(const short8*)(Am + mt * (16 * 64) + k0);
            acc2[mt] = __builtin_amdgcn_mfma_f32_16x16x32_bf16(af, bf, acc2[mt], 0, 0, 0);
        }
    }
#pragma unroll
    for (int mt = 0; mt < 4; mt++) {
        ushortx4 pk;
#pragma unroll
        for (int r = 0; r < 4; r++) {
            int f = mt * 16 + q * 4 + r;
            float v = acc2[mt][r] + ksb[32832 + f];
            pk[r] = f2bf(fmaxf(v, 0.f));
        }
        *(ushortx4*)(h2p + m * HSTR + mt * 16 + q * 4) = pk;
    }
    // h3 = Wout @ h2 (+b_out); y = h3 + skip; out += 0.1*y
    floatx4 acc3[4];
#pragma unroll
    for (int i = 0; i < 4; i++) acc3[i] = (floatx4)(0.f);
    const u16* Ao = Wo + ((size_t)b * 64 + m) * 64 + q * 8;
#pragma unroll
    for (int k0 = 0; k0 < 64; k0 += 32) {
        short8 bf = *(const short8*)(h2p + m * HSTR + k0 + q * 8);
#pragma unroll
        for (int mt = 0; mt < 4; mt++) {
            short8 af = *(const short8*)(Ao + mt * (16 * 64) + k0);
            acc3[mt] = __builtin_amdgcn_mfma_f32_16x16x32_bf16(af, bf, acc3[mt], 0, 0, 0);
        }
    }
    float* op = out + (size_t)b * NF_ * VOX_ + s0 + w * 16 + m;
#pragma unroll
    for (int mt = 0; mt < 4; mt++) {
#pragma unroll
        for (int r = 0; r < 4; r++) {
            int f = mt * 16 + q * 4 + r;
            float yv = acc3[mt][r] + ksb[36992 + f] + acc[4 + mt][r];
            float* p = op + (size_t)f * VOX_;
            *p += 0.1f * yv;
        }
    }
}

// ---------------- final channel mean ----------------
__global__ __launch_bounds__(256) void k_mean(const float* __restrict__ out,
                                              float* __restrict__ dout) {
    int idx = blockIdx.x * 256 + threadIdx.x;         // exactly 65536 threads
    int b = idx >> 12, v = idx & 4095;
    const float* p = out + (size_t)b * NF_ * VOX_ + v;
    float s = 0.f;
#pragma unroll
    for (int f = 0; f < 64; f++) s += p[(size_t)f * VOX_];
    dout[idx] = s * (1.f / 64.f);
}

extern "C" void kernel_launch(void* const* d_in, const int* in_sizes, int n_in,
                              void* d_out, int out_size, void* d_ws, size_t ws_size,
                              hipStream_t stream) {
    const float* lat  = (const float*)d_in[0];
    const float* seed = (const float*)d_in[1];
    const float* wh   = (const float*)d_in[2];
    const float* bh   = (const float*)d_in[3];
    char* ws = (char*)d_ws;
    // workspace layout (~94.2 MB total)
    float* outf = (float*)(ws);                       // 16 MB   (16x64x4096 f32)
    u16*   h    = (u16*)(ws + 16777216);              // 56 MB   (16x448x4096 bf16)
    float* ks   = (float*)(ws + 75497472);            // 4.2 MB  (16x65728 f32)
    float* part = (float*)(ws + 79704064);            // 16.8 MB (4x16x65728 f32)
    u16*   Wc   = (u16*)(ws + 96530432);              // 1.8 MB  (16x128x448 bf16)
    u16*   Wm   = (u16*)(ws + 98365440);              // 128 KB
    u16*   Wo   = (u16*)(ws + 98496512);              // 128 KB

    k_init<<<16384, 256, 0, stream>>>(seed, outf);
    k_hyper<<<dim3(257, 4), 256, 0, stream>>>(lat, wh, part);   // loop-invariant: once, not 4x
    k_redks<<<4108, 256, 0, stream>>>(part, bh, ks);
    k_wprep<<<4096, 256, 0, stream>>>(ks, Wc, Wm, Wo);
    for (int it = 0; it < 4; it++) {
        k_sobel<<<dim3(64, 16), 256, 0, stream>>>(outf, h);
        k_gemm<<<dim3(64, 16), 256, 0, stream>>>(h, Wc, Wm, Wo, ks, outf);
    }
    k_mean<<<256, 256, 0, stream>>>(outf, (float*)d_out);
}